// Round 8
// baseline (116.264 us; speedup 1.0000x reference)
//
#include <hip/hip_runtime.h>
#include <hip/hip_bf16.h>

// Problem dims (fixed by reference setup_inputs)
#define NQ 8
#define NK 1024
#define ND 64
#define NH 1024
#define NB 8
#define NT 8192

typedef float vfloat4 __attribute__((ext_vector_type(4)));

__device__ __forceinline__ unsigned bf16_rne(float f) {
    unsigned u = __float_as_uint(f);
    return (u + 0x7fffu + ((u >> 16) & 1u)) >> 16;
}

// ------------- Kernel 1: build projected codebook, tiled bf16 layout -------
// Pt[hg][q][k] = uint2 packing bf16 of
//   P[q,k,h] = bias[q][h] + sum_d codebooks[q][k][d]*W[q][h][d],  h = hg*4+{0..3}
// NO LDS: R4/R7 builds were LDS-instruction-throughput-bound (~41 us) because
// broadcast ds_read_b128 costs full ~12cyc/instr. W row addresses are
// block-uniform -> compiler emits s_load into SGPRs, FMA takes SGPR operand.
// cb row (64 f32) lives in VGPRs (no launch_bounds min-occupancy: R6 spill).
__global__ __launch_bounds__(256) void build_Pt(const float* __restrict__ cb,
                                                const float* __restrict__ W,
                                                const float* __restrict__ bias,
                                                uint2* __restrict__ Pt) {
    int q   = blockIdx.x >> 7;          // 128 blocks per q
    int kr  = (blockIdx.x >> 5) & 3;    // 4 k-ranges of 256
    int hgb = blockIdx.x & 31;          // 32 h-blocks of 32 h
    int tid = threadIdx.x;
    int k   = kr * 256 + tid;
    int h0  = hgb * 32;

    float4 c4[ND / 4];  // this thread's codebook row (64 f32, 64 VGPRs)
    const float4* csrc = (const float4*)(cb + ((size_t)q * NK + k) * ND);
#pragma unroll
    for (int i = 0; i < ND / 4; ++i) c4[i] = csrc[i];

    const float4* Wbase = (const float4*)(W + ((size_t)q * NH + h0) * ND);
    const float*  bb    = bias + q * NH + h0;

    for (int hg = 0; hg < 8; ++hg) {
        float acc[4];
#pragma unroll
        for (int hh = 0; hh < 4; ++hh) {
            int r = hg * 4 + hh;
            float a = bb[r];                      // uniform -> scalar load
            const float4* wrow = Wbase + (size_t)r * (ND / 4);
#pragma unroll
            for (int i = 0; i < ND / 4; ++i) {
                float4 w4 = wrow[i];              // uniform -> s_load_dwordx16
                a += c4[i].x * w4.x + c4[i].y * w4.y + c4[i].z * w4.z + c4[i].w * w4.w;
            }
            acc[hh] = a;
        }
        uint2 pk;
        pk.x = bf16_rne(acc[0]) | (bf16_rne(acc[1]) << 16);
        pk.y = bf16_rne(acc[2]) | (bf16_rne(acc[3]) << 16);
        int hgg = hgb * 8 + hg;
        Pt[((size_t)hgg * NQ + q) * NK + k] = pk;  // coalesced along k
    }
}

// ------------- Kernel 2: LDS-staged gather-sum, register h, x4 stores ------
// out[b,h,t] = sum_q P[q, codes[q,b,t], h]
// Block = (hg, b): stages Pt slice [8 q][1024 k][4 h] = 64 KB into LDS once,
// then streams t: thread owns 4 consecutive t; per (t,q) one ds_read_b64
// (4 bf16 h-values) accumulated into 16 registers; output written as
// nontemporal dwordx4 (no LDS transpose needed - h is register-resident).
// blockIdx&7 = b pins each batch's codes slice to one XCD's L2.
__global__ __launch_bounds__(512, 4) void gather_sum(const int* __restrict__ codes,
                                                     const uint2* __restrict__ Pt,
                                                     float* __restrict__ out) {
    int b   = blockIdx.x & 7;
    int hg  = blockIdx.x >> 3;   // 0..255
    int tid = threadIdx.x;

    __shared__ uint2 Pl[NQ * NK];  // 64 KB
    const uint4* src = (const uint4*)(Pt + (size_t)hg * NQ * NK);
    uint4* dst = (uint4*)Pl;
#pragma unroll
    for (int i = 0; i < 8; ++i) dst[tid + i * 512] = src[tid + i * 512];
    __syncthreads();

    int h0 = hg * 4;
    for (int j = 0; j < 4; ++j) {
        int t0 = j * 2048 + tid * 4;
        float acc[4][4];  // [tt][hh]
#pragma unroll
        for (int tt = 0; tt < 4; ++tt)
#pragma unroll
            for (int hh = 0; hh < 4; ++hh) acc[tt][hh] = 0.f;

#pragma unroll
        for (int q = 0; q < NQ; ++q) {
            int4 cc = *(const int4*)(codes + ((size_t)q * NB + b) * NT + t0);
#pragma unroll
            for (int tt = 0; tt < 4; ++tt) {
                int c = (tt == 0) ? cc.x : (tt == 1) ? cc.y : (tt == 2) ? cc.z : cc.w;
                uint2 v = Pl[q * NK + c];
                acc[tt][0] += __uint_as_float(v.x << 16);
                acc[tt][1] += __uint_as_float(v.x & 0xffff0000u);
                acc[tt][2] += __uint_as_float(v.y << 16);
                acc[tt][3] += __uint_as_float(v.y & 0xffff0000u);
            }
        }
#pragma unroll
        for (int hh = 0; hh < 4; ++hh) {
            vfloat4 o;
            o.x = acc[0][hh]; o.y = acc[1][hh]; o.z = acc[2][hh]; o.w = acc[3][hh];
            vfloat4* dstp = (vfloat4*)(out + ((size_t)b * NH + (h0 + hh)) * NT + t0);
            __builtin_nontemporal_store(o, dstp);
        }
    }
}

extern "C" void kernel_launch(void* const* d_in, const int* in_sizes, int n_in,
                              void* d_out, int out_size, void* d_ws, size_t ws_size,
                              hipStream_t stream) {
    const int*   codes = (const int*)d_in[0];    // [Q,B,T] int32
    const float* cb    = (const float*)d_in[1];  // [Q,K,D] f32
    const float* W     = (const float*)d_in[2];  // [Q,H,D] f32
    const float* bias  = (const float*)d_in[3];  // [Q,H] f32
    float*       out   = (float*)d_out;          // [B,H,T] f32
    uint2*       Pt    = (uint2*)d_ws;           // [256 hg][Q][K] uint2 = 16 MB

    build_Pt<<<NQ * 4 * 32, 256, 0, stream>>>(cb, W, bias, Pt);
    gather_sum<<<256 * NB, 512, 0, stream>>>(codes, Pt, out);
}

// Round 9
// 84.993 us; speedup vs baseline: 1.3679x; 1.3679x over previous
//
#include <hip/hip_runtime.h>
#include <hip/hip_bf16.h>

// Problem dims (fixed by reference setup_inputs)
#define NQ 8
#define NK 1024
#define ND 64
#define NH 1024
#define NB 8
#define NT 8192

typedef float  vfloat4 __attribute__((ext_vector_type(4)));
typedef float  f32x4   __attribute__((ext_vector_type(4)));
typedef short  short8  __attribute__((ext_vector_type(8)));

__device__ __forceinline__ unsigned bf16_rne(float f) {
    unsigned u = __float_as_uint(f);
    return (u + 0x7fffu + ((u >> 16) & 1u)) >> 16;
}

__device__ __forceinline__ short8 pack8(float4 lo, float4 hi) {
    short8 r;
    r[0] = (short)bf16_rne(lo.x); r[1] = (short)bf16_rne(lo.y);
    r[2] = (short)bf16_rne(lo.z); r[3] = (short)bf16_rne(lo.w);
    r[4] = (short)bf16_rne(hi.x); r[5] = (short)bf16_rne(hi.y);
    r[6] = (short)bf16_rne(hi.z); r[7] = (short)bf16_rne(hi.w);
    return r;
}

// ------------- Kernel 1: build projected codebook via MFMA -----------------
// Pt[hg][q][k] = uint2 packing bf16 of
//   P[q,k,h] = bias[q][h] + sum_d cb[q,k,d]*W[q,h,d],  h = hg*4+{0..3}
// Per q this is a 1024x1024x64 GEMM -> mfma_f32_16x16x32_bf16, A=W (m=h),
// B=cb (n=k), 2 K-steps. VALU builds were broadcast-bound (40-67us over
// R4-R8); MFMA does the operand broadcast in hardware. With m=h, the C/D
// layout (col=lane&15 -> k, row=(lane>>4)*4+reg -> h) gives each lane 4
// consecutive h for one k = exactly the uint2 pack, no cross-lane traffic.
// Wave: A-frags (2) register-resident, reused over 8 k-tiles. No LDS.
__global__ __launch_bounds__(256) void build_Pt(const float* __restrict__ cb,
                                                const float* __restrict__ W,
                                                const float* __restrict__ bias,
                                                uint2* __restrict__ Pt) {
    int q  = blockIdx.x >> 7;          // 8
    int hb = (blockIdx.x >> 3) & 15;   // 16 h-blocks of 64
    int kb = blockIdx.x & 7;           // 8 k-blocks of 128
    int wave = threadIdx.x >> 6, lane = threadIdx.x & 63;
    int h_tile = hb * 64 + wave * 16;
    int row16 = lane & 15, grp = lane >> 4;  // grp 0..3

    // A-frag: lane supplies A[m=row16][k = s*32 + grp*8 + j], j=0..7
    short8 afrag[2];
    const float* wrow = W + ((size_t)q * NH + h_tile + row16) * ND + grp * 8;
#pragma unroll
    for (int s = 0; s < 2; ++s) {
        float4 lo = *(const float4*)(wrow + s * 32);
        float4 hi = *(const float4*)(wrow + s * 32 + 4);
        afrag[s] = pack8(lo, hi);
    }
    // C rows this lane owns: h = h_tile + grp*4 + reg
    float bvals[4];
#pragma unroll
    for (int r = 0; r < 4; ++r) bvals[r] = bias[q * NH + h_tile + grp * 4 + r];

    int k0 = kb * 128;
    const float* cbase = cb + ((size_t)q * NK + k0 + row16) * ND + grp * 8;
    int hg = (h_tile >> 2) + grp;

#pragma unroll
    for (int t = 0; t < 8; ++t) {
        f32x4 acc = {0.f, 0.f, 0.f, 0.f};
#pragma unroll
        for (int s = 0; s < 2; ++s) {
            const float* crow = cbase + (size_t)t * 16 * ND + s * 32;
            float4 lo = *(const float4*)crow;
            float4 hi = *(const float4*)(crow + 4);
            short8 bfrag = pack8(lo, hi);  // B[n=row16][k = s*32 + grp*8 + j]
            acc = __builtin_amdgcn_mfma_f32_16x16x32_bf16(afrag[s], bfrag, acc, 0, 0, 0);
        }
        int k = k0 + t * 16 + row16;
        uint2 pk;
        pk.x = bf16_rne(acc[0] + bvals[0]) | (bf16_rne(acc[1] + bvals[1]) << 16);
        pk.y = bf16_rne(acc[2] + bvals[2]) | (bf16_rne(acc[3] + bvals[3]) << 16);
        Pt[((size_t)hg * NQ + q) * NK + k] = pk;  // lanes 0-15 contiguous in k
    }
}

// ------------- Kernel 2: LDS-staged gather-sum, register h, x4 stores ------
// out[b,h,t] = sum_q P[q, codes[q,b,t], h]
// Block = (hg, b): stages Pt slice [8 q][1024 k][4 h] = 64 KB into LDS once,
// then streams t: thread owns 4 consecutive t; per (t,q) one ds_read_b64
// (4 bf16 h-values) accumulated into 16 registers; output written as
// nontemporal dwordx4 (no LDS transpose needed - h is register-resident).
// blockIdx&7 = b pins each batch's codes slice to one XCD's L2.
__global__ __launch_bounds__(512, 4) void gather_sum(const int* __restrict__ codes,
                                                     const uint2* __restrict__ Pt,
                                                     float* __restrict__ out) {
    int b   = blockIdx.x & 7;
    int hg  = blockIdx.x >> 3;   // 0..255
    int tid = threadIdx.x;

    __shared__ uint2 Pl[NQ * NK];  // 64 KB
    const uint4* src = (const uint4*)(Pt + (size_t)hg * NQ * NK);
    uint4* dst = (uint4*)Pl;
#pragma unroll
    for (int i = 0; i < 8; ++i) dst[tid + i * 512] = src[tid + i * 512];
    __syncthreads();

    int h0 = hg * 4;
    for (int j = 0; j < 4; ++j) {
        int t0 = j * 2048 + tid * 4;
        float acc[4][4];  // [tt][hh]
#pragma unroll
        for (int tt = 0; tt < 4; ++tt)
#pragma unroll
            for (int hh = 0; hh < 4; ++hh) acc[tt][hh] = 0.f;

#pragma unroll
        for (int q = 0; q < NQ; ++q) {
            int4 cc = *(const int4*)(codes + ((size_t)q * NB + b) * NT + t0);
#pragma unroll
            for (int tt = 0; tt < 4; ++tt) {
                int c = (tt == 0) ? cc.x : (tt == 1) ? cc.y : (tt == 2) ? cc.z : cc.w;
                uint2 v = Pl[q * NK + c];
                acc[tt][0] += __uint_as_float(v.x << 16);
                acc[tt][1] += __uint_as_float(v.x & 0xffff0000u);
                acc[tt][2] += __uint_as_float(v.y << 16);
                acc[tt][3] += __uint_as_float(v.y & 0xffff0000u);
            }
        }
#pragma unroll
        for (int hh = 0; hh < 4; ++hh) {
            vfloat4 o;
            o.x = acc[0][hh]; o.y = acc[1][hh]; o.z = acc[2][hh]; o.w = acc[3][hh];
            vfloat4* dstp = (vfloat4*)(out + ((size_t)b * NH + (h0 + hh)) * NT + t0);
            __builtin_nontemporal_store(o, dstp);
        }
    }
}

extern "C" void kernel_launch(void* const* d_in, const int* in_sizes, int n_in,
                              void* d_out, int out_size, void* d_ws, size_t ws_size,
                              hipStream_t stream) {
    const int*   codes = (const int*)d_in[0];    // [Q,B,T] int32
    const float* cb    = (const float*)d_in[1];  // [Q,K,D] f32
    const float* W     = (const float*)d_in[2];  // [Q,H,D] f32
    const float* bias  = (const float*)d_in[3];  // [Q,H] f32
    float*       out   = (float*)d_out;          // [B,H,T] f32
    uint2*       Pt    = (uint2*)d_ws;           // [256 hg][Q][K] uint2 = 16 MB

    build_Pt<<<NQ * 16 * 8, 256, 0, stream>>>(cb, W, bias, Pt);
    gather_sum<<<256 * NB, 512, 0, stream>>>(codes, Pt, out);
}

// Round 10
// 84.831 us; speedup vs baseline: 1.3705x; 1.0019x over previous
//
#include <hip/hip_runtime.h>
#include <hip/hip_bf16.h>

// Problem dims (fixed by reference setup_inputs)
#define NQ 8
#define NK 1024
#define ND 64
#define NH 1024
#define NB 8
#define NT 8192

typedef float  vfloat4 __attribute__((ext_vector_type(4)));
typedef float  f32x4   __attribute__((ext_vector_type(4)));
typedef short  short8  __attribute__((ext_vector_type(8)));

// HW packed f32->bf16 (RNE). No builtin on gfx950; VALU asm is schedulable
// (non-volatile, no memory) so rule-18 hazards don't apply.
__device__ __forceinline__ unsigned cvt_pk_bf16(float lo, float hi) {
    unsigned r;
    asm("v_cvt_pk_bf16_f32 %0, %1, %2" : "=v"(r) : "v"(lo), "v"(hi));
    return r;
}

__device__ __forceinline__ short8 pack8(float4 lo, float4 hi) {
    union { unsigned u[4]; short8 s; } cv;
    cv.u[0] = cvt_pk_bf16(lo.x, lo.y);
    cv.u[1] = cvt_pk_bf16(lo.z, lo.w);
    cv.u[2] = cvt_pk_bf16(hi.x, hi.y);
    cv.u[3] = cvt_pk_bf16(hi.z, hi.w);
    return cv.s;
}

// ------------- Kernel 1: build projected codebook via MFMA -----------------
// Pt[hg][q][k] = uint2 packing bf16 of
//   P[q,k,h] = bias[q][h] + sum_d cb[q,k,d]*W[q,h,d],  h = hg*4+{0..3}
// Per q: 1024x1024x64 GEMM -> mfma_f32_16x16x32_bf16, A=W (m=h), B=cb (n=k).
// R9 showed the remaining cost was f32->bf16 packing (~4 VALU ops/value via
// bf16_rne + inserts); v_cvt_pk_bf16_f32 packs 2 values/instr.
__global__ __launch_bounds__(256) void build_Pt(const float* __restrict__ cb,
                                                const float* __restrict__ W,
                                                const float* __restrict__ bias,
                                                uint2* __restrict__ Pt) {
    int q  = blockIdx.x >> 7;          // 8
    int hb = (blockIdx.x >> 3) & 15;   // 16 h-blocks of 64
    int kb = blockIdx.x & 7;           // 8 k-blocks of 128
    int wave = threadIdx.x >> 6, lane = threadIdx.x & 63;
    int h_tile = hb * 64 + wave * 16;
    int row16 = lane & 15, grp = lane >> 4;  // grp 0..3

    // A-frag: lane supplies A[m=row16][k = s*32 + grp*8 + j], j=0..7
    short8 afrag[2];
    const float* wrow = W + ((size_t)q * NH + h_tile + row16) * ND + grp * 8;
#pragma unroll
    for (int s = 0; s < 2; ++s) {
        float4 lo = *(const float4*)(wrow + s * 32);
        float4 hi = *(const float4*)(wrow + s * 32 + 4);
        afrag[s] = pack8(lo, hi);
    }
    // C rows this lane owns: h = h_tile + grp*4 + reg
    float bvals[4];
#pragma unroll
    for (int r = 0; r < 4; ++r) bvals[r] = bias[q * NH + h_tile + grp * 4 + r];

    int k0 = kb * 128;
    const float* cbase = cb + ((size_t)q * NK + k0 + row16) * ND + grp * 8;
    int hg = (h_tile >> 2) + grp;

#pragma unroll
    for (int t = 0; t < 8; ++t) {
        f32x4 acc = {0.f, 0.f, 0.f, 0.f};
#pragma unroll
        for (int s = 0; s < 2; ++s) {
            const float* crow = cbase + (size_t)t * 16 * ND + s * 32;
            float4 lo = *(const float4*)crow;
            float4 hi = *(const float4*)(crow + 4);
            short8 bfrag = pack8(lo, hi);  // B[n=row16][k = s*32 + grp*8 + j]
            acc = __builtin_amdgcn_mfma_f32_16x16x32_bf16(afrag[s], bfrag, acc, 0, 0, 0);
        }
        int k = k0 + t * 16 + row16;
        uint2 pk;
        pk.x = cvt_pk_bf16(acc[0] + bvals[0], acc[1] + bvals[1]);
        pk.y = cvt_pk_bf16(acc[2] + bvals[2], acc[3] + bvals[3]);
        Pt[((size_t)hg * NQ + q) * NK + k] = pk;  // lanes 0-15 contiguous in k
    }
}

// ------------- Kernel 2: LDS-staged gather-sum, register h, x4 stores ------
// out[b,h,t] = sum_q P[q, codes[q,b,t], h]
// Block = (hg, b): stages Pt slice [8 q][1024 k][4 h] = 64 KB into LDS once,
// then streams t: thread owns 4 consecutive t; per (t,q) one ds_read_b64
// (4 bf16 h-values) accumulated into 16 registers; output written as
// nontemporal dwordx4 (no LDS transpose needed - h is register-resident).
// blockIdx&7 = b pins each batch's codes slice to one XCD's L2.
__global__ __launch_bounds__(512, 4) void gather_sum(const int* __restrict__ codes,
                                                     const uint2* __restrict__ Pt,
                                                     float* __restrict__ out) {
    int b   = blockIdx.x & 7;
    int hg  = blockIdx.x >> 3;   // 0..255
    int tid = threadIdx.x;

    __shared__ uint2 Pl[NQ * NK];  // 64 KB
    const uint4* src = (const uint4*)(Pt + (size_t)hg * NQ * NK);
    uint4* dst = (uint4*)Pl;
#pragma unroll
    for (int i = 0; i < 8; ++i) dst[tid + i * 512] = src[tid + i * 512];
    __syncthreads();

    int h0 = hg * 4;
    for (int j = 0; j < 4; ++j) {
        int t0 = j * 2048 + tid * 4;
        float acc[4][4];  // [tt][hh]
#pragma unroll
        for (int tt = 0; tt < 4; ++tt)
#pragma unroll
            for (int hh = 0; hh < 4; ++hh) acc[tt][hh] = 0.f;

#pragma unroll
        for (int q = 0; q < NQ; ++q) {
            int4 cc = *(const int4*)(codes + ((size_t)q * NB + b) * NT + t0);
#pragma unroll
            for (int tt = 0; tt < 4; ++tt) {
                int c = (tt == 0) ? cc.x : (tt == 1) ? cc.y : (tt == 2) ? cc.z : cc.w;
                uint2 v = Pl[q * NK + c];
                acc[tt][0] += __uint_as_float(v.x << 16);
                acc[tt][1] += __uint_as_float(v.x & 0xffff0000u);
                acc[tt][2] += __uint_as_float(v.y << 16);
                acc[tt][3] += __uint_as_float(v.y & 0xffff0000u);
            }
        }
#pragma unroll
        for (int hh = 0; hh < 4; ++hh) {
            vfloat4 o;
            o.x = acc[0][hh]; o.y = acc[1][hh]; o.z = acc[2][hh]; o.w = acc[3][hh];
            vfloat4* dstp = (vfloat4*)(out + ((size_t)b * NH + (h0 + hh)) * NT + t0);
            __builtin_nontemporal_store(o, dstp);
        }
    }
}

extern "C" void kernel_launch(void* const* d_in, const int* in_sizes, int n_in,
                              void* d_out, int out_size, void* d_ws, size_t ws_size,
                              hipStream_t stream) {
    const int*   codes = (const int*)d_in[0];    // [Q,B,T] int32
    const float* cb    = (const float*)d_in[1];  // [Q,K,D] f32
    const float* W     = (const float*)d_in[2];  // [Q,H,D] f32
    const float* bias  = (const float*)d_in[3];  // [Q,H] f32
    float*       out   = (float*)d_out;          // [B,H,T] f32
    uint2*       Pt    = (uint2*)d_ws;           // [256 hg][Q][K] uint2 = 16 MB

    build_Pt<<<NQ * 16 * 8, 256, 0, stream>>>(cb, W, bias, Pt);
    gather_sum<<<256 * NB, 512, 0, stream>>>(codes, Pt, out);
}

// Round 11
// 83.401 us; speedup vs baseline: 1.3940x; 1.0171x over previous
//
#include <hip/hip_runtime.h>
#include <hip/hip_bf16.h>

// Problem dims (fixed by reference setup_inputs)
#define NQ 8
#define NK 1024
#define ND 64
#define NH 1024
#define NB 8
#define NT 8192

typedef float  vfloat4 __attribute__((ext_vector_type(4)));
typedef float  f32x4   __attribute__((ext_vector_type(4)));
typedef short  short8  __attribute__((ext_vector_type(8)));

// HW packed f32->bf16 (RNE). No builtin on gfx950; plain (non-volatile) VALU
// asm is schedulable, rule-18 hazards don't apply.
__device__ __forceinline__ unsigned cvt_pk_bf16(float lo, float hi) {
    unsigned r;
    asm("v_cvt_pk_bf16_f32 %0, %1, %2" : "=v"(r) : "v"(lo), "v"(hi));
    return r;
}

// ------------- Kernel 0: convert cb and W to bf16 --------------------------
// blocks 0..255: cb (524288 floats); blocks 256..511: W (524288 floats).
// Thread converts 8 floats -> uint4 of 8 bf16. RNE == the pack used at MFMA
// time in R9/R10, so numerics are unchanged.
__global__ __launch_bounds__(256) void to_bf16(const float* __restrict__ cb,
                                               const float* __restrict__ W,
                                               uint4* __restrict__ cbh,
                                               uint4* __restrict__ Wh) {
    int half = blockIdx.x >> 8;
    int i    = ((blockIdx.x & 255) << 8) + threadIdx.x;  // 0..65535
    const float4* src = (const float4*)(half ? W : cb);
    float4 a = src[i * 2], b = src[i * 2 + 1];
    uint4 o;
    o.x = cvt_pk_bf16(a.x, a.y);
    o.y = cvt_pk_bf16(a.z, a.w);
    o.z = cvt_pk_bf16(b.x, b.y);
    o.w = cvt_pk_bf16(b.z, b.w);
    (half ? Wh : cbh)[i] = o;
}

// ------------- Kernel 1: build projected codebook via MFMA (bf16 in) -------
// Pt[hg][q][k] = uint2 packing bf16 of
//   P[q,k,h] = bias[q][h] + sum_d cb[q,k,d]*W[q,h,d],  h = hg*4+{0..3}
// mfma_f32_16x16x32_bf16, A=W (m=h), B=cb (n=k). bf16 inputs: one dwordx4
// per fragment, zero packing. Grid 2048 (kb of 64) -> 32 waves/CU for
// latency hiding (R10 post-mortem: build was latency-bound at 16 waves/CU).
__global__ __launch_bounds__(256) void build_Pt(const short* __restrict__ cbh,
                                                const short* __restrict__ Wh,
                                                const float* __restrict__ bias,
                                                uint2* __restrict__ Pt) {
    int q    = blockIdx.x >> 8;        // 8
    int rest = blockIdx.x & 255;
    int hb   = rest >> 4;              // 16 h-blocks of 64
    int kb   = rest & 15;              // 16 k-blocks of 64
    int wave = threadIdx.x >> 6, lane = threadIdx.x & 63;
    int h_tile = hb * 64 + wave * 16;
    int row16 = lane & 15, grp = lane >> 4;  // grp 0..3

    // A-frag: lane supplies A[m=row16][k = s*32 + grp*8 + j], j=0..7
    short8 afrag[2];
    const short* wrow = Wh + ((size_t)q * NH + h_tile + row16) * ND + grp * 8;
    afrag[0] = *(const short8*)(wrow);
    afrag[1] = *(const short8*)(wrow + 32);

    float bvals[4];
#pragma unroll
    for (int r = 0; r < 4; ++r) bvals[r] = bias[q * NH + h_tile + grp * 4 + r];

    int k0 = kb * 64;
    const short* cbase = cbh + ((size_t)q * NK + k0 + row16) * ND + grp * 8;
    int hg = (h_tile >> 2) + grp;

#pragma unroll
    for (int t = 0; t < 4; ++t) {
        const short* crow = cbase + (size_t)t * 16 * ND;
        short8 b0 = *(const short8*)(crow);
        short8 b1 = *(const short8*)(crow + 32);
        f32x4 acc = {0.f, 0.f, 0.f, 0.f};
        acc = __builtin_amdgcn_mfma_f32_16x16x32_bf16(afrag[0], b0, acc, 0, 0, 0);
        acc = __builtin_amdgcn_mfma_f32_16x16x32_bf16(afrag[1], b1, acc, 0, 0, 0);
        int k = k0 + t * 16 + row16;
        uint2 pk;
        pk.x = cvt_pk_bf16(acc[0] + bvals[0], acc[1] + bvals[1]);
        pk.y = cvt_pk_bf16(acc[2] + bvals[2], acc[3] + bvals[3]);
        Pt[((size_t)hg * NQ + q) * NK + k] = pk;  // lanes 0-15 contiguous in k
    }
}

// ------------- Kernel 2: LDS-staged gather-sum, register h, x4 stores ------
// out[b,h,t] = sum_q P[q, codes[q,b,t], h]
// Block = (hg, b): stages Pt slice [8 q][1024 k][4 h] = 64 KB into LDS once,
// then streams t: thread owns 4 consecutive t; per (t,q) one ds_read_b64
// (4 bf16 h-values) accumulated into 16 registers; output written as
// nontemporal dwordx4 (no LDS transpose needed - h is register-resident).
// blockIdx&7 = b pins each batch's codes slice to one XCD's L2.
__global__ __launch_bounds__(512, 4) void gather_sum(const int* __restrict__ codes,
                                                     const uint2* __restrict__ Pt,
                                                     float* __restrict__ out) {
    int b   = blockIdx.x & 7;
    int hg  = blockIdx.x >> 3;   // 0..255
    int tid = threadIdx.x;

    __shared__ uint2 Pl[NQ * NK];  // 64 KB
    const uint4* src = (const uint4*)(Pt + (size_t)hg * NQ * NK);
    uint4* dst = (uint4*)Pl;
#pragma unroll
    for (int i = 0; i < 8; ++i) dst[tid + i * 512] = src[tid + i * 512];
    __syncthreads();

    int h0 = hg * 4;
    for (int j = 0; j < 4; ++j) {
        int t0 = j * 2048 + tid * 4;
        float acc[4][4];  // [tt][hh]
#pragma unroll
        for (int tt = 0; tt < 4; ++tt)
#pragma unroll
            for (int hh = 0; hh < 4; ++hh) acc[tt][hh] = 0.f;

#pragma unroll
        for (int q = 0; q < NQ; ++q) {
            int4 cc = *(const int4*)(codes + ((size_t)q * NB + b) * NT + t0);
#pragma unroll
            for (int tt = 0; tt < 4; ++tt) {
                int c = (tt == 0) ? cc.x : (tt == 1) ? cc.y : (tt == 2) ? cc.z : cc.w;
                uint2 v = Pl[q * NK + c];
                acc[tt][0] += __uint_as_float(v.x << 16);
                acc[tt][1] += __uint_as_float(v.x & 0xffff0000u);
                acc[tt][2] += __uint_as_float(v.y << 16);
                acc[tt][3] += __uint_as_float(v.y & 0xffff0000u);
            }
        }
#pragma unroll
        for (int hh = 0; hh < 4; ++hh) {
            vfloat4 o;
            o.x = acc[0][hh]; o.y = acc[1][hh]; o.z = acc[2][hh]; o.w = acc[3][hh];
            vfloat4* dstp = (vfloat4*)(out + ((size_t)b * NH + (h0 + hh)) * NT + t0);
            __builtin_nontemporal_store(o, dstp);
        }
    }
}

extern "C" void kernel_launch(void* const* d_in, const int* in_sizes, int n_in,
                              void* d_out, int out_size, void* d_ws, size_t ws_size,
                              hipStream_t stream) {
    const int*   codes = (const int*)d_in[0];    // [Q,B,T] int32
    const float* cb    = (const float*)d_in[1];  // [Q,K,D] f32
    const float* W     = (const float*)d_in[2];  // [Q,H,D] f32
    const float* bias  = (const float*)d_in[3];  // [Q,H] f32
    float*       out   = (float*)d_out;          // [B,H,T] f32

    uint2* Pt  = (uint2*)d_ws;                           // 16 MB
    uint4* cbh = (uint4*)((char*)d_ws + (16u << 20));    // 1 MB bf16
    uint4* Wh  = (uint4*)((char*)d_ws + (17u << 20));    // 1 MB bf16

    to_bf16<<<512, 256, 0, stream>>>(cb, W, cbh, Wh);
    build_Pt<<<2048, 256, 0, stream>>>((const short*)cbh, (const short*)Wh, bias, Pt);
    gather_sum<<<256 * NB, 512, 0, stream>>>(codes, Pt, out);
}